// Round 14
// baseline (805.386 us; speedup 1.0000x reference)
//
#include <hip/hip_runtime.h>
#include <hip/hip_bf16.h>

typedef __attribute__((ext_vector_type(4))) int i32x4;
typedef unsigned char u8;

// ---------------- gamma = mean(|W|) + 1e-6, deterministic two-stage ----------------

__global__ void kabs_partial(const float* __restrict__ W, double* __restrict__ part, int n) {
    __shared__ double sd[256];
    const int tid = threadIdx.x;
    double s = 0.0;
    for (int i = blockIdx.x * blockDim.x + tid; i < n; i += gridDim.x * blockDim.x)
        s += (double)fabsf(W[i]);
    sd[tid] = s;
    __syncthreads();
    for (int off = 128; off > 0; off >>= 1) {
        if (tid < off) sd[tid] += sd[tid + off];
        __syncthreads();
    }
    if (tid == 0) part[blockIdx.x] = sd[0];
}

__global__ void kgamma(const double* __restrict__ part, float* __restrict__ gout, int nelem) {
    __shared__ double sd[256];
    const int tid = threadIdx.x;
    double s = part[tid] + part[tid + 256] + part[tid + 512] + part[tid + 768];
    sd[tid] = s;
    __syncthreads();
    for (int off = 128; off > 0; off >>= 1) {
        if (tid < off) sd[tid] += sd[tid + off];
        __syncthreads();
    }
    if (tid == 0) gout[0] = (float)(sd[0] / (double)nelem) + 1e-6f;
}

// ---------------- quantizers: write i8 {-1,0,+1} ----------------

__device__ __forceinline__ unsigned int qw_b(float w, float g) {
    float t = fabsf(w) / g;
    unsigned int u = __float_as_uint(w);
    return (rintf(t) >= 1.0f) ? ((u >> 31) ? 0xFFu : 0x01u) : 0u;
}

__global__ void kquant_w(const float4* __restrict__ W4, unsigned int* __restrict__ Wq,
                         const float* __restrict__ gptr, int n4) {
    int i = blockIdx.x * blockDim.x + threadIdx.x;
    if (i >= n4) return;
    const float g = *gptr;
    float4 w = W4[i];
    Wq[i] = qw_b(w.x, g) | (qw_b(w.y, g) << 8) | (qw_b(w.z, g) << 16) | (qw_b(w.w, g) << 24);
}

__device__ __forceinline__ unsigned int sgn_b(float a) {
    unsigned int u = __float_as_uint(a);
    return (u & 0x7FFFFFFFu) ? ((u >> 31) ? 0xFFu : 0x01u) : 0u;
}
__device__ __forceinline__ unsigned int sgn4(float4 v) {
    return sgn_b(v.x) | (sgn_b(v.y) << 8) | (sgn_b(v.z) << 16) | (sgn_b(v.w) << 24);
}

__global__ void kquant_x(const float4* __restrict__ X4, uint4* __restrict__ Xq, size_t n16) {
    size_t i = (size_t)blockIdx.x * blockDim.x + threadIdx.x;
    if (i >= n16) return;
    uint4 o;
    o.x = sgn4(X4[4 * i]);
    o.y = sgn4(X4[4 * i + 1]);
    o.z = sgn4(X4[4 * i + 2]);
    o.w = sgn4(X4[4 * i + 3]);
    Xq[i] = o;
}

// ---------------- 256x256 i8 MFMA GEMM, A-only LDS, 2 blocks/CU ----------------
// C[M][N] = A[M][K] * B[N][K]^T, A/B i8 {-1,0,+1}, acc i32 (exact), out f32.
// R13 post-mortem: 128KB LDS -> 1 block/CU -> all-wave barrier lockstep -> MFMA, LDS,
// VALU windows SUM (2872 cyc/phase vs 1400 max-pipe model). Fix: B (4MB, L2-resident)
// is read straight into registers (a wave's 64 lanes cover 16 rows x 64 contiguous
// bytes -> full 64B lines); LDS holds only A (64KB) -> 2 independent blocks/CU whose
// phase drift overlaps pipes (m114 mechanism).
// Per tile: {BLOAD bv (8 glob loads); STAGE A(t+1) (4 gload_lds, clamped tail);
// vmcnt(12) certify A(t); B1; ds_read m0-3; lgkm; MFMA m0-3 (compiler inserts bv
// vmcnt); ds_read m4-7; lgkm; MFMA m4-7; B2}.
// Race audit (R11 invariant: >=1 barrier between a region's last read and restage):
// A(t) reads in [B1(t),B2(t)); restage of that buffer issues in [B2(t),B1(t+1)) -- OK.
// Ledger: outstanding at certify = bv(8,new) + stage(4) + prev-stage(4,oldest) = 16;
// vmcnt(12) drains exactly prev stage, issued one full tile (~2600cyc) earlier. Never 0
// in loop; bv drains via compiler-tracked waits.

#define STAGE_A(BUF, KB)                                                                    \
    {                                                                                       \
        _Pragma("unroll")                                                                   \
        for (int h = 0; h < 2; ++h) {                                                       \
            _Pragma("unroll")                                                               \
            for (int l = 0; l < 2; ++l) {                                                   \
                const int r_ = l * 64 + srow;                                               \
                const u8* g_ = A + (size_t)(row0 + h * 128 + r_) * K + (KB) +               \
                               (sec ^ ((r_ & 7) << 4));                                     \
                __builtin_amdgcn_global_load_lds(                                           \
                    (const __attribute__((address_space(1))) unsigned int*)g_,              \
                    (__attribute__((address_space(3))) unsigned int*)&As[BUF][h][r_][sec],  \
                    16, 0, 0);                                                              \
            }                                                                               \
        }                                                                                   \
    }

#define BARRIER do { asm volatile("" ::: "memory"); __builtin_amdgcn_s_barrier(); \
                     asm volatile("" ::: "memory"); } while (0)
#define LGKM0   do { asm volatile("s_waitcnt lgkmcnt(0)" ::: "memory"); \
                     __builtin_amdgcn_sched_barrier(0); } while (0)

#define DS_READ_A4(BUF, mb, dst)                                                            \
    {                                                                                       \
        _Pragma("unroll")                                                                   \
        for (int mi = 0; mi < 4; ++mi) {                                                    \
            const int m_ = (mb) + mi;                                                       \
            const int ra = wm * 64 + (m_ & 3) * 16 + lr;                                    \
            _Pragma("unroll")                                                               \
            for (int ks = 0; ks < 2; ++ks)                                                  \
                dst[mi][ks] = *(const i32x4*)&As[BUF][m_ >> 2][ra]                          \
                                  [(ks * 64 + lk16) ^ ((ra & 7) << 4)];                     \
        }                                                                                   \
    }

#define GLOAD_B(KB)                                                                         \
    {                                                                                       \
        _Pragma("unroll")                                                                   \
        for (int n = 0; n < 4; ++n)                                                         \
            _Pragma("unroll")                                                               \
            for (int ks = 0; ks < 2; ++ks)                                                  \
                bv[n][ks] = *(const i32x4*)&Bq[(size_t)(bcol + n * 16) * K + (KB) +         \
                                               ks * 64 + lk16];                             \
    }

#define MFMA4(mb, AV)                                                                       \
    do {                                                                                    \
        __builtin_amdgcn_s_setprio(1);                                                      \
        _Pragma("unroll")                                                                   \
        for (int ks = 0; ks < 2; ++ks)                                                      \
            _Pragma("unroll")                                                               \
            for (int mi = 0; mi < 4; ++mi)                                                  \
                _Pragma("unroll")                                                           \
                for (int n = 0; n < 4; ++n)                                                 \
                    acc[(mb) + mi][n] = __builtin_amdgcn_mfma_i32_16x16x64_i8(              \
                        AV[mi][ks], bv[n][ks], acc[(mb) + mi][n], 0, 0, 0);                 \
        __builtin_amdgcn_s_setprio(0);                                                      \
    } while (0)

__global__ __launch_bounds__(512, 4) void kgemm(const u8* __restrict__ A,
                                                const u8* __restrict__ Bq,
                                                float* __restrict__ C,
                                                int M, int N, int K) {
    __shared__ u8 As[2][2][128][128];    // 64 KB -> 2 blocks/CU

    const int tid = threadIdx.x;
    const int lane = tid & 63;
    const int wid = tid >> 6;      // 0..7
    const int wm = wid >> 2;       // 0..1  (M sub-block within each half)
    const int wn = wid & 3;        // 0..3  (N sub-block)

    // T1: XCD-aware block swizzle (grid % 8 == 0 here)
    int bid = blockIdx.x;
    const int nwg = gridDim.x;
    if ((nwg & 7) == 0) bid = (bid & 7) * (nwg >> 3) + (bid >> 3);
    const int nbn = N >> 8;
    const int bm = bid / nbn, bn = bid % nbn;
    const int row0 = bm << 8, col0 = bn << 8;

    const int lr = lane & 15;
    const int lk16 = (lane >> 4) * 16;   // byte offset of this lane-group's K-chunk
    const int bcol = col0 + (wn & 1) * 64 + (wn >> 1) * 128 + lr;  // B row for this wave/lane

    // staging thread mapping: 512 threads cover 64 rows x 128 bytes per load instr
    const int srow = tid >> 3;           // 0..63
    const int sec  = (tid & 7) * 16;     // 16-byte chunk within the 128B row

    i32x4 acc[8][4] = {};
    const int NT = K >> 7;               // 16 tiles of K=128 (K % 256 == 0 guaranteed)

    // ---- prologue: stage tile0's A
    STAGE_A(0, 0);

    i32x4 bv[4][2], av0[4][2], av1[4][2];

    for (int t = 0; t < NT; ++t) {
        const int cb = t & 1, nb = cb ^ 1;
        const int kb0 = t << 7;
        const int kb1 = (t + 1 < NT ? t + 1 : NT - 1) << 7;   // clamped tail: dead re-stage

        GLOAD_B(kb0);                    // 8 reg loads (L2-resident B)
        STAGE_A(nb, kb1);                // 4 gload_lds
        asm volatile("s_waitcnt vmcnt(12)" ::: "memory");   // certify A(t) (prev stage)
        BARRIER;                         // B1: cross-wave LDS visibility of A(t)

        DS_READ_A4(cb, 0, av0);
        LGKM0;
        MFMA4(0, av0);                   // compiler inserts bv vmcnt before first use
        DS_READ_A4(cb, 4, av1);
        LGKM0;
        MFMA4(4, av1);

        BARRIER;                         // B2: separates A(t) reads from next restage
    }
    asm volatile("s_waitcnt vmcnt(0) lgkmcnt(0)" ::: "memory");

    // ---- epilogue: C/D layout col = lane&15, row = (lane>>4)*4 + reg (shape-determined,
    //      dtype-independent incl. i8). i32 -> f32 exact (|acc| <= 2048).
#pragma unroll
    for (int m = 0; m < 8; ++m) {
        const int grow = row0 + (m >> 2) * 128 + wm * 64 + (m & 3) * 16 + (lane >> 4) * 4;
#pragma unroll
        for (int n = 0; n < 4; ++n) {
            float* cp = C + (size_t)grow * N + col0 + (wn & 1) * 64 + (wn >> 1) * 128 +
                        n * 16 + (lane & 15);
#pragma unroll
            for (int r = 0; r < 4; ++r)
                cp[(size_t)r * N] = (float)acc[m][n][r];
        }
    }
}

// ---------------- correct-but-slow fallback if workspace is tiny ----------------

__global__ void knaive(const float* __restrict__ X, const float* __restrict__ W,
                       const float* __restrict__ gptr, float* __restrict__ out,
                       int N, int K) {
    size_t idx = (size_t)blockIdx.x * blockDim.x + threadIdx.x;
    const int m = (int)(idx / N), n = (int)(idx % N);
    const float g = *gptr;
    const float* xr = X + (size_t)m * K;
    const float* wrow = W + (size_t)n * K;
    float acc = 0.f;
    for (int k = 0; k < K; ++k) {
        float xv = xr[k];
        float xs = (xv > 0.f) ? 1.f : ((xv < 0.f) ? -1.f : 0.f);
        float w = wrow[k];
        float wq = (rintf(fabsf(w) / g) >= 1.f) ? ((w < 0.f) ? -1.f : 1.f) : 0.f;
        acc += xs * wq;
    }
    out[idx] = acc;
}

// ---------------- launch ----------------

extern "C" void kernel_launch(void* const* d_in, const int* in_sizes, int n_in,
                              void* d_out, int out_size, void* d_ws, size_t ws_size,
                              hipStream_t stream) {
    const float* x = (const float*)d_in[0];
    const float* W = (const float*)d_in[1];
    float* out = (float*)d_out;

    const int K = 2048;                 // in_features
    const int N = in_sizes[1] / K;      // out_features = 2048
    const int M = in_sizes[0] / K;      // 4*4096 = 16384
    const int nW = in_sizes[1];

    char* ws = (char*)d_ws;
    double* partials = (double*)ws;                       // 1024 doubles = 8 KB
    float* gamma = (float*)(ws + 8192);
    u8* wq = (u8*)(ws + 16384);
    u8* xq = (u8*)(ws + 16384 + (size_t)N * K);
    const size_t need = 16384 + (size_t)N * K + (size_t)M * K;

    kabs_partial<<<1024, 256, 0, stream>>>(W, partials, nW);
    kgamma<<<1, 256, 0, stream>>>(partials, gamma, nW);

    if (ws_size >= need && (M % 256) == 0 && (N % 256) == 0 && (K % 256) == 0) {
        kquant_w<<<nW / (256 * 4), 256, 0, stream>>>((const float4*)W, (unsigned int*)wq,
                                                     gamma, nW / 4);
        const size_t n16 = (size_t)M * K / 16;
        kquant_x<<<(unsigned)((n16 + 255) / 256), 256, 0, stream>>>(
            (const float4*)x, (uint4*)xq, n16);
        kgemm<<<(M / 256) * (N / 256), 512, 0, stream>>>(xq, wq, out, M, N, K);
    } else {
        knaive<<<(unsigned)((size_t)M * N / 256), 256, 0, stream>>>(x, W, gamma, out, N, K);
    }
}

// Round 15
// 192.408 us; speedup vs baseline: 4.1858x; 4.1858x over previous
//
#include <hip/hip_runtime.h>
#include <hip/hip_bf16.h>

typedef __attribute__((ext_vector_type(4))) int i32x4;
typedef unsigned char u8;

// ---------------- gamma = mean(|W|) + 1e-6, deterministic two-stage ----------------

__global__ void kabs_partial(const float* __restrict__ W, double* __restrict__ part, int n) {
    __shared__ double sd[256];
    const int tid = threadIdx.x;
    double s = 0.0;
    for (int i = blockIdx.x * blockDim.x + tid; i < n; i += gridDim.x * blockDim.x)
        s += (double)fabsf(W[i]);
    sd[tid] = s;
    __syncthreads();
    for (int off = 128; off > 0; off >>= 1) {
        if (tid < off) sd[tid] += sd[tid + off];
        __syncthreads();
    }
    if (tid == 0) part[blockIdx.x] = sd[0];
}

__global__ void kgamma(const double* __restrict__ part, float* __restrict__ gout, int nelem) {
    __shared__ double sd[256];
    const int tid = threadIdx.x;
    double s = part[tid] + part[tid + 256] + part[tid + 512] + part[tid + 768];
    sd[tid] = s;
    __syncthreads();
    for (int off = 128; off > 0; off >>= 1) {
        if (tid < off) sd[tid] += sd[tid + off];
        __syncthreads();
    }
    if (tid == 0) gout[0] = (float)(sd[0] / (double)nelem) + 1e-6f;
}

// ---------------- quantizers: write i8 {-1,0,+1} ----------------

__device__ __forceinline__ unsigned int qw_b(float w, float g) {
    float t = fabsf(w) / g;
    unsigned int u = __float_as_uint(w);
    return (rintf(t) >= 1.0f) ? ((u >> 31) ? 0xFFu : 0x01u) : 0u;
}

__global__ void kquant_w(const float4* __restrict__ W4, unsigned int* __restrict__ Wq,
                         const float* __restrict__ gptr, int n4) {
    int i = blockIdx.x * blockDim.x + threadIdx.x;
    if (i >= n4) return;
    const float g = *gptr;
    float4 w = W4[i];
    Wq[i] = qw_b(w.x, g) | (qw_b(w.y, g) << 8) | (qw_b(w.z, g) << 16) | (qw_b(w.w, g) << 24);
}

__device__ __forceinline__ unsigned int sgn_b(float a) {
    unsigned int u = __float_as_uint(a);
    return (u & 0x7FFFFFFFu) ? ((u >> 31) ? 0xFFu : 0x01u) : 0u;
}
__device__ __forceinline__ unsigned int sgn4(float4 v) {
    return sgn_b(v.x) | (sgn_b(v.y) << 8) | (sgn_b(v.z) << 16) | (sgn_b(v.w) << 24);
}

__global__ void kquant_x(const float4* __restrict__ X4, uint4* __restrict__ Xq, size_t n16) {
    size_t i = (size_t)blockIdx.x * blockDim.x + threadIdx.x;
    if (i >= n16) return;
    uint4 o;
    o.x = sgn4(X4[4 * i]);
    o.y = sgn4(X4[4 * i + 1]);
    o.z = sgn4(X4[4 * i + 2]);
    o.w = sgn4(X4[4 * i + 3]);
    Xq[i] = o;
}

// ---------------- 256x256 i8 MFMA GEMM, A-only LDS, B prefetched from L2 ----------------
// C[M][N] = A[M][K] * B[N][K]^T, A/B i8 {-1,0,+1}, acc i32 (exact), out f32.
// R14 post-mortem: launch_bounds(512,4) forced <=128 unified regs -> acc (128) spilled
// to scratch (VGPR_Count 64, FETCH 1.2GB, 775us). Fix: launch_bounds(512,2) (R12's
// proven contract) and keep B-from-global with bv prefetched ONE FULL TILE ahead
// (static bvA/bvB names), so the certify vmcnt(12) already drains bv before use.
// LDS holds only A (64KB): per-tile LDS work = A-reads 128KB + stage-writes 32KB
// (~1280cyc) vs R12's ~3000 -> serial-sum/tile ~4100cyc vs 5744.
// Per tile: {GLOAD_B(next bv, kb1); STAGE_A(nb, kb1); vmcnt(12); B1; ds_read m0-3;
// lgkm; MFMA m0-3; ds_read m4-7; lgkm; MFMA m4-7; B2}.
// Ledger (steady state, before vmcnt): old bvX(8)+old stage(4) + new bvY(8)+new
// stage(4) = 24 -> vmcnt(12) drains exactly the old 12 (bv for THIS tile's MFMA +
// A-stage for THIS tile), both issued one full tile (~2500cyc) earlier. Never 0 in loop.
// Race audit (>=1 barrier between region's last read and restage): A(t) reads in
// [B1(t), B2(t)); restage of that buffer issues after B2(t) in the t+1 section. OK.
// Tail: clamped kb re-stages/re-loads tile NT-1 data (dead, count-exact).

#define STAGE_A(BUF, KB)                                                                    \
    {                                                                                       \
        _Pragma("unroll")                                                                   \
        for (int h = 0; h < 2; ++h) {                                                       \
            _Pragma("unroll")                                                               \
            for (int l = 0; l < 2; ++l) {                                                   \
                const int r_ = l * 64 + srow;                                               \
                const u8* g_ = A + (size_t)(row0 + h * 128 + r_) * K + (KB) +               \
                               (sec ^ ((r_ & 7) << 4));                                     \
                __builtin_amdgcn_global_load_lds(                                           \
                    (const __attribute__((address_space(1))) unsigned int*)g_,              \
                    (__attribute__((address_space(3))) unsigned int*)&As[BUF][h][r_][sec],  \
                    16, 0, 0);                                                              \
            }                                                                               \
        }                                                                                   \
    }

#define BARRIER do { asm volatile("" ::: "memory"); __builtin_amdgcn_s_barrier(); \
                     asm volatile("" ::: "memory"); } while (0)
#define LGKM0   do { asm volatile("s_waitcnt lgkmcnt(0)" ::: "memory"); \
                     __builtin_amdgcn_sched_barrier(0); } while (0)

#define DS_READ_A4(BUF, mb, dst)                                                            \
    {                                                                                       \
        _Pragma("unroll")                                                                   \
        for (int mi = 0; mi < 4; ++mi) {                                                    \
            const int m_ = (mb) + mi;                                                       \
            const int ra = wm * 64 + (m_ & 3) * 16 + lr;                                    \
            _Pragma("unroll")                                                               \
            for (int ks = 0; ks < 2; ++ks)                                                  \
                dst[mi][ks] = *(const i32x4*)&As[BUF][m_ >> 2][ra]                          \
                                  [(ks * 64 + lk16) ^ ((ra & 7) << 4)];                     \
        }                                                                                   \
    }

#define GLOAD_B(DST, KB)                                                                    \
    {                                                                                       \
        _Pragma("unroll")                                                                   \
        for (int n = 0; n < 4; ++n)                                                         \
            _Pragma("unroll")                                                               \
            for (int ks = 0; ks < 2; ++ks)                                                  \
                DST[n][ks] = *(const i32x4*)&Bq[(size_t)(brow + n * 16) * K + (KB) +        \
                                                ks * 64 + lk16];                            \
    }

#define MFMA4(mb, AV, BV)                                                                   \
    do {                                                                                    \
        __builtin_amdgcn_s_setprio(1);                                                      \
        _Pragma("unroll")                                                                   \
        for (int ks = 0; ks < 2; ++ks)                                                      \
            _Pragma("unroll")                                                               \
            for (int mi = 0; mi < 4; ++mi)                                                  \
                _Pragma("unroll")                                                           \
                for (int n = 0; n < 4; ++n)                                                 \
                    acc[(mb) + mi][n] = __builtin_amdgcn_mfma_i32_16x16x64_i8(              \
                        AV[mi][ks], BV[n][ks], acc[(mb) + mi][n], 0, 0, 0);                 \
        __builtin_amdgcn_s_setprio(0);                                                      \
    } while (0)

// one tile: certify A(BUF)+its bv via vmcnt(12), then compute with BV
#define TILE_BODY(BUF, BV)                                                                  \
    do {                                                                                    \
        asm volatile("s_waitcnt vmcnt(12)" ::: "memory");                                   \
        BARRIER;                                                                            \
        DS_READ_A4(BUF, 0, av0);                                                            \
        LGKM0;                                                                              \
        MFMA4(0, av0, BV);                                                                  \
        DS_READ_A4(BUF, 4, av1);                                                            \
        LGKM0;                                                                              \
        MFMA4(4, av1, BV);                                                                  \
        BARRIER;                                                                            \
    } while (0)

__global__ __launch_bounds__(512, 2) void kgemm(const u8* __restrict__ A,
                                                const u8* __restrict__ Bq,
                                                float* __restrict__ C,
                                                int M, int N, int K) {
    __shared__ u8 As[2][2][128][128];    // A only: 64 KB

    const int tid = threadIdx.x;
    const int lane = tid & 63;
    const int wid = tid >> 6;      // 0..7
    const int wm = wid >> 2;       // 0..1  (M sub-block within each half)
    const int wn = wid & 3;        // 0..3  (N sub-block)

    // T1: XCD-aware block swizzle (grid % 8 == 0 here)
    int bid = blockIdx.x;
    const int nwg = gridDim.x;
    if ((nwg & 7) == 0) bid = (bid & 7) * (nwg >> 3) + (bid >> 3);
    const int nbn = N >> 8;
    const int bm = bid / nbn, bn = bid % nbn;
    const int row0 = bm << 8, col0 = bn << 8;

    const int lr = lane & 15;
    const int lk16 = (lane >> 4) * 16;   // byte offset of this lane-group's K-chunk
    const int brow = col0 + wn * 64 + lr;

    // staging thread mapping: 512 threads cover 64 rows x 128 bytes per load instr
    const int srow = tid >> 3;           // 0..63
    const int sec  = (tid & 7) * 16;     // 16-byte chunk within the 128B row

    i32x4 acc[8][4] = {};
    const int NT = K >> 7;               // 16 tiles of K=128 (K % 256 == 0 guaranteed)

    // ---- prologue: tile0's A stage + tile0's B
    STAGE_A(0, 0);
    i32x4 bvA[4][2], bvB[4][2], av0[4][2], av1[4][2];
    GLOAD_B(bvA, 0);

    for (int t = 0; t < NT; t += 2) {
        const int kb1 = (t + 1) << 7;                          // t+1 <= NT-1 (NT even)
        const int kb2 = (t + 2 < NT ? t + 2 : NT - 1) << 7;    // clamped tail (dead)

        // tile t (buf0, bvA): prefetch tile t+1's B + A
        GLOAD_B(bvB, kb1);
        STAGE_A(1, kb1);
        TILE_BODY(0, bvA);

        // tile t+1 (buf1, bvB): prefetch tile t+2's B + A
        GLOAD_B(bvA, kb2);
        STAGE_A(0, kb2);
        TILE_BODY(1, bvB);
    }
    asm volatile("s_waitcnt vmcnt(0) lgkmcnt(0)" ::: "memory");

    // ---- epilogue: C/D layout col = lane&15, row = (lane>>4)*4 + reg (shape-determined,
    //      dtype-independent incl. i8). i32 -> f32 exact (|acc| <= 2048).
#pragma unroll
    for (int m = 0; m < 8; ++m) {
        const int grow = row0 + (m >> 2) * 128 + wm * 64 + (m & 3) * 16 + (lane >> 4) * 4;
#pragma unroll
        for (int n = 0; n < 4; ++n) {
            float* cp = C + (size_t)grow * N + col0 + wn * 64 + n * 16 + (lane & 15);
#pragma unroll
            for (int r = 0; r < 4; ++r)
                cp[(size_t)r * N] = (float)acc[m][n][r];
        }
    }
}

// ---------------- correct-but-slow fallback if workspace is tiny ----------------

__global__ void knaive(const float* __restrict__ X, const float* __restrict__ W,
                       const float* __restrict__ gptr, float* __restrict__ out,
                       int N, int K) {
    size_t idx = (size_t)blockIdx.x * blockDim.x + threadIdx.x;
    const int m = (int)(idx / N), n = (int)(idx % N);
    const float g = *gptr;
    const float* xr = X + (size_t)m * K;
    const float* wrow = W + (size_t)n * K;
    float acc = 0.f;
    for (int k = 0; k < K; ++k) {
        float xv = xr[k];
        float xs = (xv > 0.f) ? 1.f : ((xv < 0.f) ? -1.f : 0.f);
        float w = wrow[k];
        float wq = (rintf(fabsf(w) / g) >= 1.f) ? ((w < 0.f) ? -1.f : 1.f) : 0.f;
        acc += xs * wq;
    }
    out[idx] = acc;
}

// ---------------- launch ----------------

extern "C" void kernel_launch(void* const* d_in, const int* in_sizes, int n_in,
                              void* d_out, int out_size, void* d_ws, size_t ws_size,
                              hipStream_t stream) {
    const float* x = (const float*)d_in[0];
    const float* W = (const float*)d_in[1];
    float* out = (float*)d_out;

    const int K = 2048;                 // in_features
    const int N = in_sizes[1] / K;      // out_features = 2048
    const int M = in_sizes[0] / K;      // 4*4096 = 16384
    const int nW = in_sizes[1];

    char* ws = (char*)d_ws;
    double* partials = (double*)ws;                       // 1024 doubles = 8 KB
    float* gamma = (float*)(ws + 8192);
    u8* wq = (u8*)(ws + 16384);
    u8* xq = (u8*)(ws + 16384 + (size_t)N * K);
    const size_t need = 16384 + (size_t)N * K + (size_t)M * K;

    kabs_partial<<<1024, 256, 0, stream>>>(W, partials, nW);
    kgamma<<<1, 256, 0, stream>>>(partials, gamma, nW);

    if (ws_size >= need && (M % 256) == 0 && (N % 256) == 0 && (K % 256) == 0) {
        kquant_w<<<nW / (256 * 4), 256, 0, stream>>>((const float4*)W, (unsigned int*)wq,
                                                     gamma, nW / 4);
        const size_t n16 = (size_t)M * K / 16;
        kquant_x<<<(unsigned)((n16 + 255) / 256), 256, 0, stream>>>(
            (const float4*)x, (uint4*)xq, n16);
        kgemm<<<(M / 256) * (N / 256), 512, 0, stream>>>(xq, wq, out, M, N, K);
    } else {
        knaive<<<(unsigned)((size_t)M * N / 256), 256, 0, stream>>>(x, W, gamma, out, N, K);
    }
}